// Round 1
// baseline (22205.080 us; speedup 1.0000x reference)
//
#include <hip/hip_runtime.h>
#include <hip/hip_cooperative_groups.h>
#include <math.h>

namespace cg = cooperative_groups;

#define LN_EPS 1e-5f

// ============================================================================
// Phase 1: precompute P = X @ Wx^T + bias  (x-part of cat = cols 512..1023 of W)
// X: [65536, 512] (m = b*512 + t). Output cols j: 0..511 -> Pa (= d_out buffer),
// 512..1023 -> Pg (workspace). BM=128 BN=128 BK=16, 256 threads, 8x8 per thread.
// ============================================================================
__global__ __launch_bounds__(256) void precompute_gemm(
    const float* __restrict__ X, const float* __restrict__ Wa,
    const float* __restrict__ Wg, const float* __restrict__ ba,
    const float* __restrict__ bg, float* __restrict__ Pa,
    float* __restrict__ Pg)
{
    __shared__ float As[16][132];
    __shared__ float Bs[16][132];
    const int bid = blockIdx.x;
    const int bn = bid & 7;    // 8 col tiles of 128
    const int bm = bid >> 3;   // 512 row tiles of 128
    const int tid = threadIdx.x;
    const int tx = tid & 15;   // col group (8 cols each)
    const int ty = tid >> 4;   // row group (8 rows each)

    const int m0 = bm * 128;
    const int n0 = bn * 128;

    // B source: row j of W, x-part starts at col 512
    const float* Wbase = (n0 < 512) ? (Wa + (size_t)n0 * 1024 + 512)
                                    : (Wg + (size_t)(n0 - 512) * 1024 + 512);

    float acc[8][8];
#pragma unroll
    for (int i = 0; i < 8; ++i)
#pragma unroll
        for (int j = 0; j < 8; ++j) acc[i][j] = 0.f;

    for (int k0 = 0; k0 < 512; k0 += 16) {
        // stage A (transposed As[k][m]) : 512 float4, 2 per thread
        {
            int idx = tid;
#pragma unroll
            for (int rep = 0; rep < 2; ++rep) {
                const int mrow = idx >> 2;
                const int kq = (idx & 3) * 4;
                const float4 v = *(const float4*)(X + (size_t)(m0 + mrow) * 512 + k0 + kq);
                As[kq + 0][mrow] = v.x;
                As[kq + 1][mrow] = v.y;
                As[kq + 2][mrow] = v.z;
                As[kq + 3][mrow] = v.w;
                idx += 256;
            }
        }
        // stage B (Bs[k][j])
        {
            int idx = tid;
#pragma unroll
            for (int rep = 0; rep < 2; ++rep) {
                const int jrow = idx >> 2;
                const int kq = (idx & 3) * 4;
                const float4 v = *(const float4*)(Wbase + (size_t)jrow * 1024 + k0 + kq);
                Bs[kq + 0][jrow] = v.x;
                Bs[kq + 1][jrow] = v.y;
                Bs[kq + 2][jrow] = v.z;
                Bs[kq + 3][jrow] = v.w;
                idx += 256;
            }
        }
        __syncthreads();
#pragma unroll
        for (int kk = 0; kk < 16; ++kk) {
            float a[8], b[8];
            const float4 a0 = *(const float4*)&As[kk][ty * 8];
            const float4 a1 = *(const float4*)&As[kk][ty * 8 + 4];
            const float4 b0 = *(const float4*)&Bs[kk][tx * 8];
            const float4 b1 = *(const float4*)&Bs[kk][tx * 8 + 4];
            a[0] = a0.x; a[1] = a0.y; a[2] = a0.z; a[3] = a0.w;
            a[4] = a1.x; a[5] = a1.y; a[6] = a1.z; a[7] = a1.w;
            b[0] = b0.x; b[1] = b0.y; b[2] = b0.z; b[3] = b0.w;
            b[4] = b1.x; b[5] = b1.y; b[6] = b1.z; b[7] = b1.w;
#pragma unroll
            for (int i = 0; i < 8; ++i)
#pragma unroll
                for (int j = 0; j < 8; ++j) acc[i][j] += a[i] * b[j];
        }
        __syncthreads();
    }

    // epilogue: add bias, store
    const bool isA = (n0 < 512);
#pragma unroll
    for (int i = 0; i < 8; ++i) {
        const int m = m0 + ty * 8 + i;
        const int jbase = n0 + tx * 8;
#pragma unroll
        for (int j = 0; j < 8; ++j) {
            const int jg = jbase + j;
            const float bia = isA ? ba[jg] : bg[jg - 512];
            const float v = acc[i][j] + bia;
            if (isA) Pa[(size_t)m * 512 + jg] = v;
            else     Pg[(size_t)m * 512 + (jg - 512)] = v;
        }
    }
}

// ============================================================================
// Phase 2: recurrent scan. Cooperative kernel, 256 blocks x 256 threads.
// Block (gr,gc): batch rows gr*16..+16, h-cols gc*16..+16. Weight h-part slice
// resident in LDS. Deferred layernorm: write unnormalized htilde + slotted
// partial stats; normalize on load next step. One grid.sync per step.
// Pa lives in `po` (= d_out); out[.., t-1, ..] is written during step t.
// ============================================================================
__global__ __launch_bounds__(256, 1) void scan_kernel(
    const float* __restrict__ Wa, const float* __restrict__ Wg,
    const float* __restrict__ gamma, const float* __restrict__ beta,
    float* po,                       // d_out: holds Pa, overwritten with out
    const float* __restrict__ Pg,    // [65536,512] in ws
    float* __restrict__ Htil,        // [2][128][512] in ws
    float2* __restrict__ statp)      // [2][32][128] in ws
{
    __shared__ float wa_s[16][516];
    __shared__ float wg_s[16][516];
    __shared__ float hn[16][516];
    __shared__ float gam[512], bet[512];
    __shared__ float mu_s[16], rs_s[16];

    cg::grid_group grid = cg::this_grid();

    const int bid = blockIdx.x;
    const int gc = bid & 31;             // 32 col tiles
    const int gr = bid >> 5;             // 8 row tiles
    const int tid = threadIdx.x;
    const int jh = tid & 15;             // local col 0..15
    const int r = tid >> 4;              // local row 0..15
    const int row = gr * 16 + r;         // global batch row
    const int col = gc * 16 + jh;        // global h col

    // load weight slices (h-part = cols 0..511 of W rows [gc*16 .. +16))
    for (int idx = tid; idx < 16 * 128; idx += 256) {
        const int c = idx >> 7;
        const int q = (idx & 127) * 4;
        *(float4*)&wa_s[c][q] = *(const float4*)(Wa + (size_t)(gc * 16 + c) * 1024 + q);
        *(float4*)&wg_s[c][q] = *(const float4*)(Wg + (size_t)(gc * 16 + c) * 1024 + q);
    }
    for (int idx = tid; idx < 512; idx += 256) { gam[idx] = gamma[idx]; bet[idx] = beta[idx]; }
    __syncthreads();

    float hprev = 0.f;

    for (int t = 0; t < 512; ++t) {
        float a_acc = 0.f, g_acc = 0.f;
        if (t > 0) {
            const int pb = (t - 1) & 1;
            // finalize stats of htilde_{t-1} for this block's 16 rows
            if (tid < 16) {
                float s1 = 0.f, s2 = 0.f;
                const float2* sp = statp + (size_t)pb * 4096 + (gr * 16 + tid);
#pragma unroll 4
                for (int g2 = 0; g2 < 32; ++g2) {
                    const float2 v = sp[(size_t)g2 * 128];
                    s1 += v.x; s2 += v.y;
                }
                const float mu = s1 * (1.f / 512.f);
                const float var = s2 * (1.f / 512.f) - mu * mu;
                mu_s[tid] = mu;
                rs_s[tid] = rsqrtf(var + LN_EPS);
            }
            __syncthreads();
            // write normalized out[row][t-1][col] from own registered htilde
            {
                const float v = (hprev - mu_s[r]) * rs_s[r] * gam[col] + bet[col];
                po[(size_t)row * 262144 + (size_t)(t - 1) * 512 + col] = v;
            }
            // load + normalize htilde_{t-1}[16 rows][512] into LDS
            const float* hsrc = Htil + (size_t)pb * 65536;
            for (int idx = tid; idx < 16 * 128; idx += 256) {
                const int rr = idx >> 7;
                const int q = (idx & 127) * 4;
                float4 v = *(const float4*)(hsrc + (size_t)(gr * 16 + rr) * 512 + q);
                const float m = mu_s[rr], rs = rs_s[rr];
                v.x = (v.x - m) * rs * gam[q + 0] + bet[q + 0];
                v.y = (v.y - m) * rs * gam[q + 1] + bet[q + 1];
                v.z = (v.z - m) * rs * gam[q + 2] + bet[q + 2];
                v.w = (v.w - m) * rs * gam[q + 3] + bet[q + 3];
                *(float4*)&hn[rr][q] = v;
            }
            __syncthreads();
            // GEMM: a,g over K=512
            const float* hrow = &hn[r][0];
            const float* war = &wa_s[jh][0];
            const float* wgr = &wg_s[jh][0];
            float aa = 0.f, gg = 0.f;
#pragma unroll 4
            for (int k4 = 0; k4 < 128; ++k4) {
                const float4 h4 = *(const float4*)(hrow + k4 * 4);
                const float4 w4 = *(const float4*)(war + k4 * 4);
                const float4 v4 = *(const float4*)(wgr + k4 * 4);
                aa += h4.x * w4.x + h4.y * w4.y + h4.z * w4.z + h4.w * w4.w;
                gg += h4.x * v4.x + h4.y * v4.y + h4.z * v4.z + h4.w * v4.w;
            }
            a_acc = aa; g_acc = gg;
        }
        // add precomputed x-part (+bias)
        const size_t pidx = ((size_t)row * 512 + (size_t)t) * 512 + col;
        a_acc += po[pidx];
        g_acc += Pg[pidx];
        // gated blend
        const float alpha = 1.f / (1.f + expf(-g_acc));
        const float ht = alpha * tanhf(a_acc) + (1.f - alpha) * a_acc;
        hprev = ht;
        // store unnormalized htilde
        Htil[(size_t)(t & 1) * 65536 + (size_t)row * 512 + col] = ht;
        // partial stats over this block's 16 cols (reduce 16 consecutive lanes)
        float s1 = ht, s2 = ht * ht;
#pragma unroll
        for (int m = 1; m < 16; m <<= 1) {
            s1 += __shfl_xor(s1, m);
            s2 += __shfl_xor(s2, m);
        }
        if (jh == 0) {
            statp[(size_t)(t & 1) * 4096 + (size_t)gc * 128 + row] = make_float2(s1, s2);
        }
        grid.sync();
    }

    // epilogue: write out[.., 511, ..]
    {
        if (tid < 16) {
            float s1 = 0.f, s2 = 0.f;
            const float2* sp = statp + (size_t)1 * 4096 + (gr * 16 + tid);
#pragma unroll 4
            for (int g2 = 0; g2 < 32; ++g2) {
                const float2 v = sp[(size_t)g2 * 128];
                s1 += v.x; s2 += v.y;
            }
            const float mu = s1 * (1.f / 512.f);
            const float var = s2 * (1.f / 512.f) - mu * mu;
            mu_s[tid] = mu;
            rs_s[tid] = rsqrtf(var + LN_EPS);
        }
        __syncthreads();
        const float v = (hprev - mu_s[r]) * rs_s[r] * gam[col] + bet[col];
        po[(size_t)row * 262144 + (size_t)511 * 512 + col] = v;
    }
}

extern "C" void kernel_launch(void* const* d_in, const int* in_sizes, int n_in,
                              void* d_out, int out_size, void* d_ws, size_t ws_size,
                              hipStream_t stream) {
    (void)in_sizes; (void)n_in; (void)out_size; (void)ws_size;
    const float* X     = (const float*)d_in[0];
    const float* Wa    = (const float*)d_in[1];
    const float* Wg    = (const float*)d_in[2];
    const float* ba    = (const float*)d_in[3];
    const float* bg    = (const float*)d_in[4];
    const float* gamma = (const float*)d_in[5];
    const float* beta  = (const float*)d_in[6];
    float* out = (float*)d_out;

    char* ws = (char*)d_ws;
    float*  Pg    = (float*)ws;                                // 134217728 B
    float*  Htil  = (float*)(ws + 134217728);                  // 524288 B
    float2* statp = (float2*)(ws + 134217728 + 524288);        // 65536 B

    // Phase 1: P = X @ Wx^T + bias ; Pa -> d_out, Pg -> ws
    precompute_gemm<<<dim3(4096), dim3(256), 0, stream>>>(X, Wa, Wg, ba, bg, out, Pg);

    // Phase 2: cooperative recurrent scan (256 blocks = 1 per CU)
    const float* Pg_c = Pg;
    void* args[] = { (void*)&Wa, (void*)&Wg, (void*)&gamma, (void*)&beta,
                     (void*)&out, (void*)&Pg_c, (void*)&Htil, (void*)&statp };
    hipLaunchCooperativeKernel((const void*)scan_kernel, dim3(256), dim3(256),
                               args, 0, stream);
}

// Round 2
// 6567.214 us; speedup vs baseline: 3.3812x; 3.3812x over previous
//
#include <hip/hip_runtime.h>
#include <math.h>

typedef _Float16 f16;
typedef _Float16 f16x2 __attribute__((ext_vector_type(2)));

union U32H2 { unsigned u; f16x2 h; };

#define LN_EPS 1e-5f

// ============================================================================
// Phase 0: pack h-part of weights (cols 0..511) into f16-pair arrays laid out
// for coalesced dwordx4 reads in the scan:
//   WP[k8][j][q] (uint) = ( W[j][8*k8+2*q] , W[j][8*k8+2*q+1] ) as 2 x f16
// i.e. uint4 at (k8, j) covers ks 8*k8 .. 8*k8+7 of column j.
// ============================================================================
__global__ __launch_bounds__(256) void pack_weights(
    const float* __restrict__ Wa, const float* __restrict__ Wg,
    unsigned* __restrict__ WaP, unsigned* __restrict__ WgP)
{
    const int idx = blockIdx.x * 256 + threadIdx.x;   // 0 .. 131071
    const int q  = idx & 3;
    const int j  = (idx >> 2) & 511;
    const int k8 = idx >> 11;
    const int k  = 8 * k8 + 2 * q;
    {
        U32H2 u;
        u.h[0] = (f16)Wa[(size_t)j * 1024 + k];
        u.h[1] = (f16)Wa[(size_t)j * 1024 + k + 1];
        WaP[idx] = u.u;
    }
    {
        U32H2 u;
        u.h[0] = (f16)Wg[(size_t)j * 1024 + k];
        u.h[1] = (f16)Wg[(size_t)j * 1024 + k + 1];
        WgP[idx] = u.u;
    }
}

// ============================================================================
// Phase 1: precompute P = X @ Wx^T + bias  (x-part of cat = cols 512..1023).
// Pa (cols 0..511) -> d_out (fp32); Pg (cols 512..1023) -> ws as f16.
// ============================================================================
__global__ __launch_bounds__(256) void precompute_gemm(
    const float* __restrict__ X, const float* __restrict__ Wa,
    const float* __restrict__ Wg, const float* __restrict__ ba,
    const float* __restrict__ bg, float* __restrict__ Pa,
    f16* __restrict__ Pgh)
{
    __shared__ float As[16][132];
    __shared__ float Bs[16][132];
    const int bid = blockIdx.x;
    const int bn = bid & 7;
    const int bm = bid >> 3;
    const int tid = threadIdx.x;
    const int tx = tid & 15;
    const int ty = tid >> 4;

    const int m0 = bm * 128;
    const int n0 = bn * 128;

    const float* Wbase = (n0 < 512) ? (Wa + (size_t)n0 * 1024 + 512)
                                    : (Wg + (size_t)(n0 - 512) * 1024 + 512);

    float acc[8][8];
#pragma unroll
    for (int i = 0; i < 8; ++i)
#pragma unroll
        for (int j = 0; j < 8; ++j) acc[i][j] = 0.f;

    for (int k0 = 0; k0 < 512; k0 += 16) {
        {
            int idx = tid;
#pragma unroll
            for (int rep = 0; rep < 2; ++rep) {
                const int mrow = idx >> 2;
                const int kq = (idx & 3) * 4;
                const float4 v = *(const float4*)(X + (size_t)(m0 + mrow) * 512 + k0 + kq);
                As[kq + 0][mrow] = v.x;
                As[kq + 1][mrow] = v.y;
                As[kq + 2][mrow] = v.z;
                As[kq + 3][mrow] = v.w;
                idx += 256;
            }
        }
        {
            int idx = tid;
#pragma unroll
            for (int rep = 0; rep < 2; ++rep) {
                const int jrow = idx >> 2;
                const int kq = (idx & 3) * 4;
                const float4 v = *(const float4*)(Wbase + (size_t)jrow * 1024 + k0 + kq);
                Bs[kq + 0][jrow] = v.x;
                Bs[kq + 1][jrow] = v.y;
                Bs[kq + 2][jrow] = v.z;
                Bs[kq + 3][jrow] = v.w;
                idx += 256;
            }
        }
        __syncthreads();
#pragma unroll
        for (int kk = 0; kk < 16; ++kk) {
            float a[8], b[8];
            const float4 a0 = *(const float4*)&As[kk][ty * 8];
            const float4 a1 = *(const float4*)&As[kk][ty * 8 + 4];
            const float4 b0 = *(const float4*)&Bs[kk][tx * 8];
            const float4 b1 = *(const float4*)&Bs[kk][tx * 8 + 4];
            a[0] = a0.x; a[1] = a0.y; a[2] = a0.z; a[3] = a0.w;
            a[4] = a1.x; a[5] = a1.y; a[6] = a1.z; a[7] = a1.w;
            b[0] = b0.x; b[1] = b0.y; b[2] = b0.z; b[3] = b0.w;
            b[4] = b1.x; b[5] = b1.y; b[6] = b1.z; b[7] = b1.w;
#pragma unroll
            for (int i = 0; i < 8; ++i)
#pragma unroll
                for (int j = 0; j < 8; ++j) acc[i][j] += a[i] * b[j];
        }
        __syncthreads();
    }

    const bool isA = (n0 < 512);
#pragma unroll
    for (int i = 0; i < 8; ++i) {
        const int m = m0 + ty * 8 + i;
        const int jbase = n0 + tx * 8;
#pragma unroll
        for (int j = 0; j < 8; ++j) {
            const int jg = jbase + j;
            const float bia = isA ? ba[jg] : bg[jg - 512];
            const float v = acc[i][j] + bia;
            if (isA) Pa[(size_t)m * 512 + jg] = v;
            else     Pgh[(size_t)m * 512 + (jg - 512)] = (f16)v;
        }
    }
}

// ============================================================================
// Phase 2: recurrent scan — NO grid sync. Batch rows are independent; block
// bid owns rows (2*bid, 2*bid+1) and runs all 512 steps locally. Thread j
// owns h-col j for both rows & both gates. Weights f16-packed, L2-resident.
// ============================================================================
__global__ __launch_bounds__(512) void scan2(
    const uint4* __restrict__ WaP, const uint4* __restrict__ WgP,
    const float* __restrict__ gamma, const float* __restrict__ beta,
    float* po,                        // d_out: holds Pa (fp32), overwritten with out
    const f16* __restrict__ Pgh)      // [65536,512] f16 in ws
{
    __shared__ f16 hs[2][512];
    __shared__ float4 red[8];

    const int tid = threadIdx.x;      // 0..511 == h col j
    const int j = tid;
    const int r0 = blockIdx.x * 2;
    const int r1 = r0 + 1;
    const float gj = gamma[j];
    const float bj = beta[j];

    hs[0][j] = (f16)0.f;
    hs[1][j] = (f16)0.f;
    __syncthreads();

    const uint4* __restrict__ wa = WaP + j;
    const uint4* __restrict__ wg = WgP + j;
    const f16x2* __restrict__ h0p = (const f16x2*)&hs[0][0];
    const f16x2* __restrict__ h1p = (const f16x2*)&hs[1][0];

    for (int t = 0; t < 512; ++t) {
        // prefetch x-parts for this step
        const size_t p0 = ((size_t)r0 * 512 + (size_t)t) * 512 + j;
        const size_t p1 = ((size_t)r1 * 512 + (size_t)t) * 512 + j;
        const float pa0 = po[p0];
        const float pa1 = po[p1];
        const float pg0 = (float)Pgh[p0];
        const float pg1 = (float)Pgh[p1];

        // h-part matvec: a,g for both rows, K=512, f16 dot2 with fp32 accum
        float a0 = 0.f, g0 = 0.f, a1 = 0.f, g1 = 0.f;
#pragma unroll 4
        for (int k8 = 0; k8 < 64; ++k8) {
            const uint4 WA = wa[(size_t)k8 * 512];
            const uint4 WG = wg[(size_t)k8 * 512];
            const f16x2 h00 = h0p[4 * k8 + 0], h01 = h0p[4 * k8 + 1];
            const f16x2 h02 = h0p[4 * k8 + 2], h03 = h0p[4 * k8 + 3];
            const f16x2 h10 = h1p[4 * k8 + 0], h11 = h1p[4 * k8 + 1];
            const f16x2 h12 = h1p[4 * k8 + 2], h13 = h1p[4 * k8 + 3];
            U32H2 wa0, wa1, wa2, wa3, wg0, wg1, wg2, wg3;
            wa0.u = WA.x; wa1.u = WA.y; wa2.u = WA.z; wa3.u = WA.w;
            wg0.u = WG.x; wg1.u = WG.y; wg2.u = WG.z; wg3.u = WG.w;
            a0 = __builtin_amdgcn_fdot2(wa0.h, h00, a0, false);
            a0 = __builtin_amdgcn_fdot2(wa1.h, h01, a0, false);
            a0 = __builtin_amdgcn_fdot2(wa2.h, h02, a0, false);
            a0 = __builtin_amdgcn_fdot2(wa3.h, h03, a0, false);
            g0 = __builtin_amdgcn_fdot2(wg0.h, h00, g0, false);
            g0 = __builtin_amdgcn_fdot2(wg1.h, h01, g0, false);
            g0 = __builtin_amdgcn_fdot2(wg2.h, h02, g0, false);
            g0 = __builtin_amdgcn_fdot2(wg3.h, h03, g0, false);
            a1 = __builtin_amdgcn_fdot2(wa0.h, h10, a1, false);
            a1 = __builtin_amdgcn_fdot2(wa1.h, h11, a1, false);
            a1 = __builtin_amdgcn_fdot2(wa2.h, h12, a1, false);
            a1 = __builtin_amdgcn_fdot2(wa3.h, h13, a1, false);
            g1 = __builtin_amdgcn_fdot2(wg0.h, h10, g1, false);
            g1 = __builtin_amdgcn_fdot2(wg1.h, h11, g1, false);
            g1 = __builtin_amdgcn_fdot2(wg2.h, h12, g1, false);
            g1 = __builtin_amdgcn_fdot2(wg3.h, h13, g1, false);
        }
        a0 += pa0; a1 += pa1; g0 += pg0; g1 += pg1;

        // gated blend: h~ = alpha*tanh(a) + (1-alpha)*a
        const float alpha0 = 1.f / (1.f + __expf(-g0));
        const float alpha1 = 1.f / (1.f + __expf(-g1));
        const float ac0 = fminf(fmaxf(a0, -15.f), 15.f);
        const float ac1 = fminf(fmaxf(a1, -15.f), 15.f);
        const float e0 = __expf(2.f * ac0);
        const float e1 = __expf(2.f * ac1);
        const float th0 = (e0 - 1.f) / (e0 + 1.f);
        const float th1 = (e1 - 1.f) / (e1 + 1.f);
        const float ht0 = alpha0 * (th0 - a0) + a0;
        const float ht1 = alpha1 * (th1 - a1) + a1;

        // block-wide layernorm stats per row
        float s0 = ht0, ss0 = ht0 * ht0, s1 = ht1, ss1 = ht1 * ht1;
#pragma unroll
        for (int m = 1; m < 64; m <<= 1) {
            s0 += __shfl_xor(s0, m);
            ss0 += __shfl_xor(ss0, m);
            s1 += __shfl_xor(s1, m);
            ss1 += __shfl_xor(ss1, m);
        }
        if ((tid & 63) == 0) red[tid >> 6] = make_float4(s0, ss0, s1, ss1);
        __syncthreads();
        float S0 = 0.f, SS0 = 0.f, S1 = 0.f, SS1 = 0.f;
#pragma unroll
        for (int w = 0; w < 8; ++w) {
            const float4 v = red[w];
            S0 += v.x; SS0 += v.y; S1 += v.z; SS1 += v.w;
        }
        const float mu0 = S0 * (1.f / 512.f);
        const float mu1 = S1 * (1.f / 512.f);
        const float var0 = SS0 * (1.f / 512.f) - mu0 * mu0;
        const float var1 = SS1 * (1.f / 512.f) - mu1 * mu1;
        const float rs0 = rsqrtf(var0 + LN_EPS);
        const float rs1 = rsqrtf(var1 + LN_EPS);

        const float hn0 = (ht0 - mu0) * rs0 * gj + bj;
        const float hn1 = (ht1 - mu1) * rs1 * gj + bj;

        // write output (overwrites Pa slot for this (row,t,j) — same thread)
        po[p0] = hn0;
        po[p1] = hn1;
        // publish h for next step
        hs[0][j] = (f16)hn0;
        hs[1][j] = (f16)hn1;
        __syncthreads();
    }
}

extern "C" void kernel_launch(void* const* d_in, const int* in_sizes, int n_in,
                              void* d_out, int out_size, void* d_ws, size_t ws_size,
                              hipStream_t stream) {
    (void)in_sizes; (void)n_in; (void)out_size; (void)ws_size;
    const float* X     = (const float*)d_in[0];
    const float* Wa    = (const float*)d_in[1];
    const float* Wg    = (const float*)d_in[2];
    const float* ba    = (const float*)d_in[3];
    const float* bg    = (const float*)d_in[4];
    const float* gamma = (const float*)d_in[5];
    const float* beta  = (const float*)d_in[6];
    float* out = (float*)d_out;

    char* ws = (char*)d_ws;
    f16*      Pgh = (f16*)ws;                       // 65536*512*2 = 67108864 B
    unsigned* WaP = (unsigned*)(ws + 67108864);     // 131072*4 = 524288 B
    unsigned* WgP = (unsigned*)(ws + 67108864 + 524288);

    // Phase 0: pack h-part weights to f16 pairs (coalesced layout)
    pack_weights<<<dim3(512), dim3(256), 0, stream>>>(Wa, Wg, WaP, WgP);

    // Phase 1: P = X @ Wx^T + bias ; Pa -> d_out (fp32), Pg -> ws (f16)
    precompute_gemm<<<dim3(4096), dim3(256), 0, stream>>>(X, Wa, Wg, ba, bg, out, Pgh);

    // Phase 2: independent per-row-pair recurrence, 64 blocks x 512 threads
    scan2<<<dim3(64), dim3(512), 0, stream>>>((const uint4*)WaP, (const uint4*)WgP,
                                              gamma, beta, out, Pgh);
}

// Round 3
// 3995.383 us; speedup vs baseline: 5.5577x; 1.6437x over previous
//
#include <hip/hip_runtime.h>
#include <math.h>

typedef _Float16 f16;
typedef _Float16 f16x8 __attribute__((ext_vector_type(8)));
typedef float f32x4 __attribute__((ext_vector_type(4)));

union U32H2 { unsigned u; f16 h[2]; };
union UV4H8 { uint4 u; f16x8 h; f16 e[8]; };

#define LN_EPS 1e-5f

// ============================================================================
// init: zero the group sync counters (must run every launch — replay safety)
// ============================================================================
__global__ void init_cnt(unsigned* cnt) { cnt[threadIdx.x] = 0u; }

// ============================================================================
// Phase 0: pack h-part weights (W[col][k], k<512) into MFMA B-fragment order.
// WP[tile][kf][lane] (uint4 = 8 f16): element j = W[col][k] with
//   col = (tile%32)*16 + (lane&15),  k = kf*32 + (lane>>4)*8 + j
// tiles 0..31 = a-gate col-tiles, 32..63 = g-gate.
// ============================================================================
__global__ __launch_bounds__(256) void pack_wfrags(
    const float* __restrict__ Wa, const float* __restrict__ Wg,
    uint4* __restrict__ WP)
{
    const int t = blockIdx.x * 256 + threadIdx.x;   // 0..65535
    const int lane = t & 63;
    const int kf = (t >> 6) & 15;
    const int tile = t >> 10;
    const float* W = (tile < 32) ? Wa : Wg;
    const int col = (tile & 31) * 16 + (lane & 15);
    const int k0 = kf * 32 + (lane >> 4) * 8;
    const float* src = W + (size_t)col * 1024 + k0;
    UV4H8 u;
#pragma unroll
    for (int j = 0; j < 8; ++j) u.e[j] = (f16)src[j];
    WP[t] = u.u;
}

// ============================================================================
// Phase 1: precompute P = X @ Wx^T + bias (x-part = cols 512..1023 of W).
// Pa -> d_out (fp32); Pg -> ws as f16. (unchanged from round 2 — correct)
// ============================================================================
__global__ __launch_bounds__(256) void precompute_gemm(
    const float* __restrict__ X, const float* __restrict__ Wa,
    const float* __restrict__ Wg, const float* __restrict__ ba,
    const float* __restrict__ bg, float* __restrict__ Pa,
    f16* __restrict__ Pgh)
{
    __shared__ float As[16][132];
    __shared__ float Bs[16][132];
    const int bid = blockIdx.x;
    const int bn = bid & 7;
    const int bm = bid >> 3;
    const int tid = threadIdx.x;
    const int tx = tid & 15;
    const int ty = tid >> 4;

    const int m0 = bm * 128;
    const int n0 = bn * 128;

    const float* Wbase = (n0 < 512) ? (Wa + (size_t)n0 * 1024 + 512)
                                    : (Wg + (size_t)(n0 - 512) * 1024 + 512);

    float acc[8][8];
#pragma unroll
    for (int i = 0; i < 8; ++i)
#pragma unroll
        for (int j = 0; j < 8; ++j) acc[i][j] = 0.f;

    for (int k0 = 0; k0 < 512; k0 += 16) {
        {
            int idx = tid;
#pragma unroll
            for (int rep = 0; rep < 2; ++rep) {
                const int mrow = idx >> 2;
                const int kq = (idx & 3) * 4;
                const float4 v = *(const float4*)(X + (size_t)(m0 + mrow) * 512 + k0 + kq);
                As[kq + 0][mrow] = v.x;
                As[kq + 1][mrow] = v.y;
                As[kq + 2][mrow] = v.z;
                As[kq + 3][mrow] = v.w;
                idx += 256;
            }
        }
        {
            int idx = tid;
#pragma unroll
            for (int rep = 0; rep < 2; ++rep) {
                const int jrow = idx >> 2;
                const int kq = (idx & 3) * 4;
                const float4 v = *(const float4*)(Wbase + (size_t)jrow * 1024 + k0 + kq);
                Bs[kq + 0][jrow] = v.x;
                Bs[kq + 1][jrow] = v.y;
                Bs[kq + 2][jrow] = v.z;
                Bs[kq + 3][jrow] = v.w;
                idx += 256;
            }
        }
        __syncthreads();
#pragma unroll
        for (int kk = 0; kk < 16; ++kk) {
            float a[8], b[8];
            const float4 a0 = *(const float4*)&As[kk][ty * 8];
            const float4 a1 = *(const float4*)&As[kk][ty * 8 + 4];
            const float4 b0 = *(const float4*)&Bs[kk][tx * 8];
            const float4 b1 = *(const float4*)&Bs[kk][tx * 8 + 4];
            a[0] = a0.x; a[1] = a0.y; a[2] = a0.z; a[3] = a0.w;
            a[4] = a1.x; a[5] = a1.y; a[6] = a1.z; a[7] = a1.w;
            b[0] = b0.x; b[1] = b0.y; b[2] = b0.z; b[3] = b0.w;
            b[4] = b1.x; b[5] = b1.y; b[6] = b1.z; b[7] = b1.w;
#pragma unroll
            for (int i = 0; i < 8; ++i)
#pragma unroll
                for (int j = 0; j < 8; ++j) acc[i][j] += a[i] * b[j];
        }
        __syncthreads();
    }

    const bool isA = (n0 < 512);
#pragma unroll
    for (int i = 0; i < 8; ++i) {
        const int m = m0 + ty * 8 + i;
        const int jbase = n0 + tx * 8;
#pragma unroll
        for (int j = 0; j < 8; ++j) {
            const int jg = jbase + j;
            const float bia = isA ? ba[jg] : bg[jg - 512];
            const float v = acc[i][j] + bia;
            if (isA) Pa[(size_t)m * 512 + jg] = v;
            else     Pgh[(size_t)m * 512 + (jg - 512)] = (f16)v;
        }
    }
}

// ============================================================================
// Phase 2: recurrent scan. 64 blocks = 8 row-groups x 8 col-blocks.
// Block: 16 batch rows x 64 h-cols (both gates). Weights live in REGISTERS
// (64 VGPR of pre-packed B-frags per lane). Per step: 16 ds_read A-frags +
// 16 MFMA per wave; blocks in a row-group exchange pre-LN h~ (f16) + partial
// stats via L3 with an 8-way release/acquire flag barrier (double-buffered
// by t parity). No grid.sync.
// ============================================================================
__global__ __launch_bounds__(512, 1) void scan3(
    const uint4* __restrict__ WP, const float* __restrict__ gamma,
    const float* __restrict__ beta, float* po, const f16* __restrict__ Pgh,
    f16* __restrict__ Hex,      // [2][8][16][512] f16
    float2* __restrict__ HexS,  // [2][8][8][16] float2
    unsigned* cnt)              // [8] counters, stride 64 uints
{
    __shared__ f16 hn[16][520];       // normalized h, padded (bank-safe)
    __shared__ float Dx[16][132];     // a|g exchange between waves
    __shared__ float gam[512], bet[512];
    __shared__ float mu_s[16], rs_s[16];

    const int tid = threadIdx.x;
    const int wv = tid >> 6, lane = tid & 63;
    const int bid = blockIdx.x;
    const int rg = bid >> 3, cb = bid & 7;
    const int c0 = cb * 64;
    const int r0 = rg * 16;

    // ---- load static weight fragments into registers (once) ----
    const int tile = (wv < 4) ? (cb * 4 + wv) : (32 + cb * 4 + (wv - 4));
    f16x8 Bf[16];
#pragma unroll
    for (int kf = 0; kf < 16; ++kf) {
        UV4H8 u; u.u = WP[(size_t)(tile * 16 + kf) * 64 + lane];
        Bf[kf] = u.h;
    }

    for (int i = tid; i < 16 * 260; i += 512) ((unsigned*)hn)[i] = 0u;
    { gam[tid & 511] = gamma[tid & 511]; bet[tid & 511] = beta[tid & 511]; }
    __syncthreads();

    const int rb = tid >> 5, u = tid & 31;   // blend/rebuild role: row rb, col-chunk u
    const int cba = u * 2;
    const int arow = lane & 15;
    const int akb = (lane >> 4) * 8;
    unsigned* mycnt = cnt + rg * 64;

    for (int t = 0; t < 512; ++t) {
        const int par = t & 1;
        const size_t orow = ((size_t)(r0 + rb) * 512 + (size_t)t) * 512 + c0 + cba;
        // prefetch x-parts (consumed after MFMA)
        const float2 pa = *(const float2*)(po + orow);
        U32H2 pg; pg.u = *(const unsigned*)(Pgh + orow);

        // ---- MFMA: this wave's 16-col tile (a or g), K=512 ----
        f32x4 acc = {0.f, 0.f, 0.f, 0.f};
#pragma unroll
        for (int kf = 0; kf < 16; ++kf) {
            const f16x8 Af = *(const f16x8*)&hn[arow][kf * 32 + akb];
            acc = __builtin_amdgcn_mfma_f32_16x16x32_f16(Af, Bf[kf], acc, 0, 0, 0);
        }
        {
            const int dr = (lane >> 4) * 4;
            const int dc = wv * 16 + (lane & 15);   // 0..63 = a, 64..127 = g
            Dx[dr + 0][dc] = acc[0];
            Dx[dr + 1][dc] = acc[1];
            Dx[dr + 2][dc] = acc[2];
            Dx[dr + 3][dc] = acc[3];
        }
        __syncthreads();

        // ---- gated blend (2 outputs per thread: row rb, cols c0+cba, +1) ----
        const float a0 = Dx[rb][cba] + pa.x;
        const float a1 = Dx[rb][cba + 1] + pa.y;
        const float g0 = Dx[rb][64 + cba] + (float)pg.h[0];
        const float g1 = Dx[rb][64 + cba + 1] + (float)pg.h[1];
        const float al0 = 1.f / (1.f + __expf(-g0));
        const float al1 = 1.f / (1.f + __expf(-g1));
        const float ac0 = fminf(fmaxf(a0, -15.f), 15.f);
        const float ac1 = fminf(fmaxf(a1, -15.f), 15.f);
        const float e0 = __expf(2.f * ac0), e1 = __expf(2.f * ac1);
        const float th0 = (e0 - 1.f) / (e0 + 1.f);
        const float th1 = (e1 - 1.f) / (e1 + 1.f);
        const float ht0 = al0 * (th0 - a0) + a0;
        const float ht1 = al1 * (th1 - a1) + a1;

        // partial LN stats over this block's 64 cols (32 lanes per row)
        float s1 = ht0 + ht1, s2 = ht0 * ht0 + ht1 * ht1;
#pragma unroll
        for (int m = 1; m < 32; m <<= 1) { s1 += __shfl_xor(s1, m); s2 += __shfl_xor(s2, m); }

        // publish h~ (f16) + stats
        {
            U32H2 hw; hw.h[0] = (f16)ht0; hw.h[1] = (f16)ht1;
            *(unsigned*)(Hex + (((size_t)par * 8 + rg) * 16 + rb) * 512 + c0 + cba) = hw.u;
        }
        if (u == 0) HexS[(((size_t)par * 8 + rg) * 8 + cb) * 16 + rb] = make_float2(s1, s2);
        __syncthreads();

        // ---- 8-way group barrier (release/acquire through L3) ----
        if (tid == 0) {
            __threadfence();
            __hip_atomic_fetch_add(mycnt, 1u, __ATOMIC_RELEASE, __HIP_MEMORY_SCOPE_AGENT);
            const unsigned target = 8u * (unsigned)(t + 1);
            while (__hip_atomic_load(mycnt, __ATOMIC_ACQUIRE, __HIP_MEMORY_SCOPE_AGENT) < target)
                __builtin_amdgcn_s_sleep(8);
        }
        __syncthreads();

        // ---- full-row LN stats ----
        if (tid < 16) {
            float S1 = 0.f, S2 = 0.f;
            const float2* sp = HexS + ((size_t)par * 8 + rg) * 128 + tid;
#pragma unroll
            for (int q = 0; q < 8; ++q) { const float2 v = sp[q * 16]; S1 += v.x; S2 += v.y; }
            const float mu = S1 * (1.f / 512.f);
            const float var = S2 * (1.f / 512.f) - mu * mu;
            mu_s[tid] = mu;
            rs_s[tid] = rsqrtf(var + LN_EPS);
        }
        __syncthreads();

        const float mu = mu_s[rb], rs = rs_s[rb];
        // write output (own 64 cols, fp32 h~ precision)
        po[orow]     = (ht0 - mu) * rs * gam[c0 + cba] + bet[c0 + cba];
        po[orow + 1] = (ht1 - mu) * rs * gam[c0 + cba + 1] + bet[c0 + cba + 1];

        // rebuild normalized h into LDS: thread -> row rb, cols u*16..+15
        {
            const f16* hsrc = Hex + (((size_t)par * 8 + rg) * 16 + rb) * 512 + u * 16;
            const uint4 q0 = *(const uint4*)hsrc;
            const uint4 q1 = *(const uint4*)(hsrc + 8);
            const unsigned wq[8] = {q0.x, q0.y, q0.z, q0.w, q1.x, q1.y, q1.z, q1.w};
            const float* gp = &gam[u * 16];
            const float* bp = &bet[u * 16];
            UV4H8 o0, o1;
#pragma unroll
            for (int i = 0; i < 8; ++i) {
                U32H2 hh; hh.u = wq[i];
                const float v0 = ((float)hh.h[0] - mu) * rs * gp[2 * i] + bp[2 * i];
                const float v1 = ((float)hh.h[1] - mu) * rs * gp[2 * i + 1] + bp[2 * i + 1];
                if (i < 4) { o0.e[2 * i] = (f16)v0; o0.e[2 * i + 1] = (f16)v1; }
                else { o1.e[2 * (i - 4)] = (f16)v0; o1.e[2 * (i - 4) + 1] = (f16)v1; }
            }
            *(uint4*)&hn[rb][u * 16] = o0.u;
            *(uint4*)&hn[rb][u * 16 + 8] = o1.u;
        }
        __syncthreads();
    }
}

extern "C" void kernel_launch(void* const* d_in, const int* in_sizes, int n_in,
                              void* d_out, int out_size, void* d_ws, size_t ws_size,
                              hipStream_t stream) {
    (void)in_sizes; (void)n_in; (void)out_size; (void)ws_size;
    const float* X     = (const float*)d_in[0];
    const float* Wa    = (const float*)d_in[1];
    const float* Wg    = (const float*)d_in[2];
    const float* ba    = (const float*)d_in[3];
    const float* bg    = (const float*)d_in[4];
    const float* gamma = (const float*)d_in[5];
    const float* beta  = (const float*)d_in[6];
    float* out = (float*)d_out;

    char* ws = (char*)d_ws;
    f16*      Pgh  = (f16*)ws;                        // 67108864 B
    uint4*    WP   = (uint4*)(ws + 67108864);         // 1048576 B
    f16*      Hex  = (f16*)(ws + 68157440);           // 262144 B
    float2*   HexS = (float2*)(ws + 68419584);        // 16384 B
    unsigned* cnt  = (unsigned*)(ws + 68435968);      // 2048 B

    init_cnt<<<dim3(1), dim3(512), 0, stream>>>(cnt);
    pack_wfrags<<<dim3(256), dim3(256), 0, stream>>>(Wa, Wg, WP);
    precompute_gemm<<<dim3(4096), dim3(256), 0, stream>>>(X, Wa, Wg, ba, bg, out, Pgh);

    void* args[] = { (void*)&WP, (void*)&gamma, (void*)&beta, (void*)&out,
                     (void*)&Pgh, (void*)&Hex, (void*)&HexS, (void*)&cnt };
    hipLaunchCooperativeKernel((const void*)scan3, dim3(64), dim3(512),
                               args, 0, stream);
}

// Round 4
// 3003.140 us; speedup vs baseline: 7.3940x; 1.3304x over previous
//
#include <hip/hip_runtime.h>
#include <math.h>

typedef _Float16 f16;
typedef _Float16 f16x8 __attribute__((ext_vector_type(8)));
typedef float f32x4 __attribute__((ext_vector_type(4)));

union U32H2 { unsigned u; f16 h[2]; };
union UV4H8 { uint4 u; f16x8 h; f16 e[8]; };
union UF2 { unsigned long long u; float2 f; };

#define LN_EPS 1e-5f

// ---- coherent (cache-bypassing) exchange primitives: relaxed agent-scope ----
__device__ __forceinline__ void st_u32(unsigned* p, unsigned v) {
    __hip_atomic_store(p, v, __ATOMIC_RELAXED, __HIP_MEMORY_SCOPE_AGENT);
}
__device__ __forceinline__ unsigned ld_u32(const unsigned* p) {
    return __hip_atomic_load(p, __ATOMIC_RELAXED, __HIP_MEMORY_SCOPE_AGENT);
}
__device__ __forceinline__ void st_u64(unsigned long long* p, unsigned long long v) {
    __hip_atomic_store(p, v, __ATOMIC_RELAXED, __HIP_MEMORY_SCOPE_AGENT);
}
__device__ __forceinline__ unsigned long long ld_u64(const unsigned long long* p) {
    return __hip_atomic_load(p, __ATOMIC_RELAXED, __HIP_MEMORY_SCOPE_AGENT);
}

// ============================================================================
// init: zero the per-rowgroup step flags (every launch — replay safety)
// ============================================================================
__global__ void init_cnt(unsigned* flags) { flags[threadIdx.x] = 0u; }

// ============================================================================
// Phase 0: pack h-part weights (W[col][k], k<512) into MFMA B-fragment order.
//   col = (tile%32)*16 + (lane&15),  k = kf*32 + (lane>>4)*8 + j
// tiles 0..31 = a-gate col-tiles, 32..63 = g-gate.
// ============================================================================
__global__ __launch_bounds__(256) void pack_wfrags(
    const float* __restrict__ Wa, const float* __restrict__ Wg,
    uint4* __restrict__ WP)
{
    const int t = blockIdx.x * 256 + threadIdx.x;   // 0..65535
    const int lane = t & 63;
    const int kf = (t >> 6) & 15;
    const int tile = t >> 10;
    const float* W = (tile < 32) ? Wa : Wg;
    const int col = (tile & 31) * 16 + (lane & 15);
    const int k0 = kf * 32 + (lane >> 4) * 8;
    const float* src = W + (size_t)col * 1024 + k0;
    UV4H8 u;
#pragma unroll
    for (int j = 0; j < 8; ++j) u.e[j] = (f16)src[j];
    WP[t] = u.u;
}

// ============================================================================
// Phase 1: precompute P = X @ Wx^T + bias (x-part = cols 512..1023 of W).
// Pa -> d_out (fp32); Pg -> ws as f16. (unchanged — verified)
// ============================================================================
__global__ __launch_bounds__(256) void precompute_gemm(
    const float* __restrict__ X, const float* __restrict__ Wa,
    const float* __restrict__ Wg, const float* __restrict__ ba,
    const float* __restrict__ bg, float* __restrict__ Pa,
    f16* __restrict__ Pgh)
{
    __shared__ float As[16][132];
    __shared__ float Bs[16][132];
    const int bid = blockIdx.x;
    const int bn = bid & 7;
    const int bm = bid >> 3;
    const int tid = threadIdx.x;
    const int tx = tid & 15;
    const int ty = tid >> 4;

    const int m0 = bm * 128;
    const int n0 = bn * 128;

    const float* Wbase = (n0 < 512) ? (Wa + (size_t)n0 * 1024 + 512)
                                    : (Wg + (size_t)(n0 - 512) * 1024 + 512);

    float acc[8][8];
#pragma unroll
    for (int i = 0; i < 8; ++i)
#pragma unroll
        for (int j = 0; j < 8; ++j) acc[i][j] = 0.f;

    for (int k0 = 0; k0 < 512; k0 += 16) {
        {
            int idx = tid;
#pragma unroll
            for (int rep = 0; rep < 2; ++rep) {
                const int mrow = idx >> 2;
                const int kq = (idx & 3) * 4;
                const float4 v = *(const float4*)(X + (size_t)(m0 + mrow) * 512 + k0 + kq);
                As[kq + 0][mrow] = v.x;
                As[kq + 1][mrow] = v.y;
                As[kq + 2][mrow] = v.z;
                As[kq + 3][mrow] = v.w;
                idx += 256;
            }
        }
        {
            int idx = tid;
#pragma unroll
            for (int rep = 0; rep < 2; ++rep) {
                const int jrow = idx >> 2;
                const int kq = (idx & 3) * 4;
                const float4 v = *(const float4*)(Wbase + (size_t)jrow * 1024 + k0 + kq);
                Bs[kq + 0][jrow] = v.x;
                Bs[kq + 1][jrow] = v.y;
                Bs[kq + 2][jrow] = v.z;
                Bs[kq + 3][jrow] = v.w;
                idx += 256;
            }
        }
        __syncthreads();
#pragma unroll
        for (int kk = 0; kk < 16; ++kk) {
            float a[8], b[8];
            const float4 a0 = *(const float4*)&As[kk][ty * 8];
            const float4 a1 = *(const float4*)&As[kk][ty * 8 + 4];
            const float4 b0 = *(const float4*)&Bs[kk][tx * 8];
            const float4 b1 = *(const float4*)&Bs[kk][tx * 8 + 4];
            a[0] = a0.x; a[1] = a0.y; a[2] = a0.z; a[3] = a0.w;
            a[4] = a1.x; a[5] = a1.y; a[6] = a1.z; a[7] = a1.w;
            b[0] = b0.x; b[1] = b0.y; b[2] = b0.z; b[3] = b0.w;
            b[4] = b1.x; b[5] = b1.y; b[6] = b1.z; b[7] = b1.w;
#pragma unroll
            for (int i = 0; i < 8; ++i)
#pragma unroll
                for (int j = 0; j < 8; ++j) acc[i][j] += a[i] * b[j];
        }
        __syncthreads();
    }

    const bool isA = (n0 < 512);
#pragma unroll
    for (int i = 0; i < 8; ++i) {
        const int m = m0 + ty * 8 + i;
        const int jbase = n0 + tx * 8;
#pragma unroll
        for (int j = 0; j < 8; ++j) {
            const int jg = jbase + j;
            const float bia = isA ? ba[jg] : bg[jg - 512];
            const float v = acc[i][j] + bia;
            if (isA) Pa[(size_t)m * 512 + jg] = v;
            else     Pgh[(size_t)m * 512 + (jg - 512)] = (f16)v;
        }
    }
}

// ============================================================================
// Phase 2: recurrent scan. 64 blocks = 8 row-groups x 8 col-blocks.
// Register-resident weights. Cross-block exchange via cache-bypassing relaxed
// agent atomics (sc0/sc1) through L3 — NO fences, NO L2 flushes. Flag barrier:
// per-wave vmcnt(0) + block barrier + one relaxed flag store; 8-lane spin.
// hn LDS tile XOR-swizzled ( byte ^= (row&7)<<4 ) on both write and read.
// ============================================================================
__global__ __launch_bounds__(512, 1) void scan4(
    const uint4* __restrict__ WP, const float* __restrict__ gamma,
    const float* __restrict__ beta, float* po, const f16* __restrict__ Pgh,
    f16* __restrict__ Hex,      // [2][8][16][512] f16
    float2* __restrict__ HexS,  // [2][8][8][16] float2
    unsigned* __restrict__ flags) // [8][8] stride-16 dwords
{
    __shared__ f16 hn[16][512];       // swizzled
    __shared__ float Dx[16][132];
    __shared__ float gam[512], bet[512];
    __shared__ float mu_s[16], rs_s[16];

    const int tid = threadIdx.x;
    const int wv = tid >> 6, lane = tid & 63;
    const int bid = blockIdx.x;
    const int rg = bid >> 3, cb = bid & 7;
    const int c0 = cb * 64;
    const int r0 = rg * 16;

    // ---- load static weight fragments into registers (once) ----
    const int tile = (wv < 4) ? (cb * 4 + wv) : (32 + cb * 4 + (wv - 4));
    f16x8 Bf[16];
#pragma unroll
    for (int kf = 0; kf < 16; ++kf) {
        UV4H8 uu; uu.u = WP[(size_t)(tile * 16 + kf) * 64 + lane];
        Bf[kf] = uu.h;
    }

    for (int i = tid; i < 16 * 256; i += 512) ((unsigned*)hn)[i] = 0u;
    { gam[tid & 511] = gamma[tid & 511]; bet[tid & 511] = beta[tid & 511]; }
    __syncthreads();

    const int rb = tid >> 5, u = tid & 31;   // blend role: row rb, col-chunk u
    const int cba = u * 2;
    const int arow = lane & 15;
    const int hi16 = (lane >> 4) * 16;
    const int swzr = (arow & 7) << 4;
    const int swzw = (rb & 7) << 4;
    const char* hrow_r = (const char*)&hn[arow][0];
    char* hrow_w = (char*)&hn[rb][0];

    for (int t = 0; t < 512; ++t) {
        const int par = t & 1;
        const size_t orow = ((size_t)(r0 + rb) * 512 + (size_t)t) * 512 + c0 + cba;
        // prefetch x-parts (consumed after MFMA)
        const float2 pa = *(const float2*)(po + orow);
        U32H2 pg; pg.u = *(const unsigned*)(Pgh + orow);

        // ---- MFMA: this wave's 16-col tile (a or g), K=512 ----
        f32x4 acc = {0.f, 0.f, 0.f, 0.f};
#pragma unroll
        for (int kf = 0; kf < 16; ++kf) {
            const f16x8 Af = *(const f16x8*)(hrow_r + ((kf * 64 + hi16) ^ swzr));
            acc = __builtin_amdgcn_mfma_f32_16x16x32_f16(Af, Bf[kf], acc, 0, 0, 0);
        }
        {
            const int dr = (lane >> 4) * 4;
            const int dc = wv * 16 + (lane & 15);   // 0..63 = a, 64..127 = g
            Dx[dr + 0][dc] = acc[0];
            Dx[dr + 1][dc] = acc[1];
            Dx[dr + 2][dc] = acc[2];
            Dx[dr + 3][dc] = acc[3];
        }
        __syncthreads();

        // ---- gated blend (row rb, cols c0+cba, +1) ----
        const float a0 = Dx[rb][cba] + pa.x;
        const float a1 = Dx[rb][cba + 1] + pa.y;
        const float g0 = Dx[rb][64 + cba] + (float)pg.h[0];
        const float g1 = Dx[rb][64 + cba + 1] + (float)pg.h[1];
        const float al0 = 1.f / (1.f + __expf(-g0));
        const float al1 = 1.f / (1.f + __expf(-g1));
        const float ac0 = fminf(fmaxf(a0, -15.f), 15.f);
        const float ac1 = fminf(fmaxf(a1, -15.f), 15.f);
        const float e0 = __expf(2.f * ac0), e1 = __expf(2.f * ac1);
        const float th0 = (e0 - 1.f) / (e0 + 1.f);
        const float th1 = (e1 - 1.f) / (e1 + 1.f);
        const float ht0 = al0 * (th0 - a0) + a0;
        const float ht1 = al1 * (th1 - a1) + a1;

        // partial LN stats over this block's 64 cols (32 lanes per row)
        float s1 = ht0 + ht1, s2 = ht0 * ht0 + ht1 * ht1;
#pragma unroll
        for (int m = 1; m < 32; m <<= 1) { s1 += __shfl_xor(s1, m); s2 += __shfl_xor(s2, m); }

        // ---- publish h~ (f16) + stats via coherent stores ----
        {
            U32H2 hw; hw.h[0] = (f16)ht0; hw.h[1] = (f16)ht1;
            st_u32((unsigned*)(Hex + (((size_t)par * 8 + rg) * 16 + rb) * 512 + c0 + cba), hw.u);
        }
        if (u == 0) {
            UF2 s; s.f = make_float2(s1, s2);
            st_u64((unsigned long long*)&HexS[(((size_t)par * 8 + rg) * 8 + cb) * 16 + rb], s.u);
        }
        asm volatile("s_waitcnt vmcnt(0) lgkmcnt(0)" ::: "memory");
        __syncthreads();

        // ---- flag barrier across the 8 col-blocks of this row-group ----
        if (tid == 0) st_u32(&flags[(rg * 8 + cb) * 16], (unsigned)(t + 1));
        if (tid < 8) {
            while (ld_u32(&flags[(rg * 8 + tid) * 16]) < (unsigned)(t + 1))
                __builtin_amdgcn_s_sleep(1);
        }
        __syncthreads();

        // ---- issue Hex row reload early (hides under stats phase) ----
        const unsigned long long* hsrc =
            (const unsigned long long*)(Hex + (((size_t)par * 8 + rg) * 16 + rb) * 512 + u * 16);
        const unsigned long long q0 = ld_u64(hsrc + 0);
        const unsigned long long q1 = ld_u64(hsrc + 1);
        const unsigned long long q2 = ld_u64(hsrc + 2);
        const unsigned long long q3 = ld_u64(hsrc + 3);

        // ---- full-row LN stats ----
        if (tid < 16) {
            float S1 = 0.f, S2 = 0.f;
            const unsigned long long* sp =
                (const unsigned long long*)(HexS + ((size_t)par * 8 + rg) * 128 + tid);
#pragma unroll
            for (int q = 0; q < 8; ++q) {
                UF2 v; v.u = ld_u64(sp + (size_t)q * 16);
                S1 += v.f.x; S2 += v.f.y;
            }
            const float mu = S1 * (1.f / 512.f);
            const float var = S2 * (1.f / 512.f) - mu * mu;
            mu_s[tid] = mu;
            rs_s[tid] = rsqrtf(var + LN_EPS);
        }
        __syncthreads();

        const float mu = mu_s[rb], rs = rs_s[rb];
        // write output (own cols, fp32 h~ precision)
        po[orow]     = (ht0 - mu) * rs * gam[c0 + cba] + bet[c0 + cba];
        po[orow + 1] = (ht1 - mu) * rs * gam[c0 + cba + 1] + bet[c0 + cba + 1];

        // rebuild normalized h into LDS (swizzled): row rb, cols u*16..+15
        {
            const unsigned wq[8] = {
                (unsigned)q0, (unsigned)(q0 >> 32), (unsigned)q1, (unsigned)(q1 >> 32),
                (unsigned)q2, (unsigned)(q2 >> 32), (unsigned)q3, (unsigned)(q3 >> 32)};
            const float* gp = &gam[u * 16];
            const float* bp = &bet[u * 16];
            UV4H8 o0, o1;
#pragma unroll
            for (int i = 0; i < 8; ++i) {
                U32H2 hh; hh.u = wq[i];
                const float v0 = ((float)hh.h[0] - mu) * rs * gp[2 * i] + bp[2 * i];
                const float v1 = ((float)hh.h[1] - mu) * rs * gp[2 * i + 1] + bp[2 * i + 1];
                if (i < 4) { o0.e[2 * i] = (f16)v0; o0.e[2 * i + 1] = (f16)v1; }
                else { o1.e[2 * (i - 4)] = (f16)v0; o1.e[2 * (i - 4) + 1] = (f16)v1; }
            }
            *(uint4*)(hrow_w + ((u * 32) ^ swzw)) = o0.u;
            *(uint4*)(hrow_w + ((u * 32 + 16) ^ swzw)) = o1.u;
        }
        __syncthreads();
    }
}

extern "C" void kernel_launch(void* const* d_in, const int* in_sizes, int n_in,
                              void* d_out, int out_size, void* d_ws, size_t ws_size,
                              hipStream_t stream) {
    (void)in_sizes; (void)n_in; (void)out_size; (void)ws_size;
    const float* X     = (const float*)d_in[0];
    const float* Wa    = (const float*)d_in[1];
    const float* Wg    = (const float*)d_in[2];
    const float* ba    = (const float*)d_in[3];
    const float* bg    = (const float*)d_in[4];
    const float* gamma = (const float*)d_in[5];
    const float* beta  = (const float*)d_in[6];
    float* out = (float*)d_out;

    char* ws = (char*)d_ws;
    f16*      Pgh   = (f16*)ws;                        // 67108864 B
    uint4*    WP    = (uint4*)(ws + 67108864);         // 1048576 B
    f16*      Hex   = (f16*)(ws + 68157440);           // 262144 B
    float2*   HexS  = (float2*)(ws + 68419584);        // 16384 B
    unsigned* flags = (unsigned*)(ws + 68435968);      // 4096 B

    init_cnt<<<dim3(1), dim3(1024), 0, stream>>>(flags);
    pack_wfrags<<<dim3(256), dim3(256), 0, stream>>>(Wa, Wg, WP);
    precompute_gemm<<<dim3(4096), dim3(256), 0, stream>>>(X, Wa, Wg, ba, bg, out, Pgh);

    void* args[] = { (void*)&WP, (void*)&gamma, (void*)&beta, (void*)&out,
                     (void*)&Pgh, (void*)&Hex, (void*)&HexS, (void*)&flags };
    hipLaunchCooperativeKernel((const void*)scan4, dim3(64), dim3(512),
                               args, 0, stream);
}

// Round 5
// 2753.930 us; speedup vs baseline: 8.0631x; 1.0905x over previous
//
#include <hip/hip_runtime.h>
#include <math.h>

typedef _Float16 f16;
typedef _Float16 f16x8 __attribute__((ext_vector_type(8)));
typedef float f32x4 __attribute__((ext_vector_type(4)));
typedef unsigned long long u64;

union U32H2 { unsigned u; f16 h[2]; };
union UV4H8 { uint4 u; f16x8 h; f16 e[8]; };
union UFI { unsigned u; float f; };

#define LN_EPS 1e-5f

// ---- cache-bypassing (L3-coherent) 8-byte atomics, relaxed agent scope ----
__device__ __forceinline__ void st_u64g(u64* p, u64 v) {
    __hip_atomic_store(p, v, __ATOMIC_RELAXED, __HIP_MEMORY_SCOPE_AGENT);
}
__device__ __forceinline__ u64 ld_u64g(const u64* p) {
    return __hip_atomic_load(p, __ATOMIC_RELAXED, __HIP_MEMORY_SCOPE_AGENT);
}

// ============================================================================
// init: zero tagged-exchange buffers (every launch — replay safety)
// ============================================================================
__global__ __launch_bounds__(256) void init_ex(u64* p, int n) {
    const int i = blockIdx.x * 256 + threadIdx.x;
    if (i < n) p[i] = 0ull;
}

// ============================================================================
// Phase 0a: pack h-part weights, GAMMA-FOLDED, into MFMA B-fragment order.
//   W'[col][k] = W[col][k] * gamma[k]
//   col = (tile%32)*16 + (lane&15),  k = kf*32 + (lane>>4)*8 + j
// tiles 0..31 = a-gate, 32..63 = g-gate.
// ============================================================================
__global__ __launch_bounds__(256) void pack_wfrags(
    const float* __restrict__ Wa, const float* __restrict__ Wg,
    const float* __restrict__ gamma, uint4* __restrict__ WP)
{
    const int t = blockIdx.x * 256 + threadIdx.x;   // 0..65535
    const int lane = t & 63;
    const int kf = (t >> 6) & 15;
    const int tile = t >> 10;
    const float* W = (tile < 32) ? Wa : Wg;
    const int col = (tile & 31) * 16 + (lane & 15);
    const int k0 = kf * 32 + (lane >> 4) * 8;
    const float* src = W + (size_t)col * 1024 + k0;
    UV4H8 u;
#pragma unroll
    for (int j = 0; j < 8; ++j) u.e[j] = (f16)(src[j] * gamma[k0 + j]);
    WP[t] = u.u;
}

// ============================================================================
// Phase 0b: constant vectors for the LN-fold:
//   Cvec[0][o]=Wa[o]·beta  Cvec[1][o]=Wa[o]·gamma  Cvec[2][o]=Wg[o]·beta
//   Cvec[3][o]=Wg[o]·gamma   (h-part k<512, fp32 exact)
// ============================================================================
__global__ __launch_bounds__(64) void precompute_consts(
    const float* __restrict__ Wa, const float* __restrict__ Wg,
    const float* __restrict__ gamma, const float* __restrict__ beta,
    float* __restrict__ Cvec)
{
    const int o = blockIdx.x;
    const int l = threadIdx.x;
    const float* wa = Wa + (size_t)o * 1024;
    const float* wg = Wg + (size_t)o * 1024;
    float ca = 0.f, ga = 0.f, cg = 0.f, gg = 0.f;
    for (int k = l; k < 512; k += 64) {
        const float bk = beta[k], gk = gamma[k], a = wa[k], g = wg[k];
        ca += a * bk; ga += a * gk; cg += g * bk; gg += g * gk;
    }
#pragma unroll
    for (int m = 1; m < 64; m <<= 1) {
        ca += __shfl_xor(ca, m); ga += __shfl_xor(ga, m);
        cg += __shfl_xor(cg, m); gg += __shfl_xor(gg, m);
    }
    if (l == 0) {
        Cvec[o] = ca; Cvec[512 + o] = ga; Cvec[1024 + o] = cg; Cvec[1536 + o] = gg;
    }
}

// ============================================================================
// Phase 1: precompute P = X @ Wx^T + bias (x-part = cols 512..1023 of W).
// Pa -> d_out (fp32); Pg -> ws as f16. (unchanged — verified)
// ============================================================================
__global__ __launch_bounds__(256) void precompute_gemm(
    const float* __restrict__ X, const float* __restrict__ Wa,
    const float* __restrict__ Wg, const float* __restrict__ ba,
    const float* __restrict__ bg, float* __restrict__ Pa,
    f16* __restrict__ Pgh)
{
    __shared__ float As[16][132];
    __shared__ float Bs[16][132];
    const int bid = blockIdx.x;
    const int bn = bid & 7;
    const int bm = bid >> 3;
    const int tid = threadIdx.x;
    const int tx = tid & 15;
    const int ty = tid >> 4;

    const int m0 = bm * 128;
    const int n0 = bn * 128;

    const float* Wbase = (n0 < 512) ? (Wa + (size_t)n0 * 1024 + 512)
                                    : (Wg + (size_t)(n0 - 512) * 1024 + 512);

    float acc[8][8];
#pragma unroll
    for (int i = 0; i < 8; ++i)
#pragma unroll
        for (int j = 0; j < 8; ++j) acc[i][j] = 0.f;

    for (int k0 = 0; k0 < 512; k0 += 16) {
        {
            int idx = tid;
#pragma unroll
            for (int rep = 0; rep < 2; ++rep) {
                const int mrow = idx >> 2;
                const int kq = (idx & 3) * 4;
                const float4 v = *(const float4*)(X + (size_t)(m0 + mrow) * 512 + k0 + kq);
                As[kq + 0][mrow] = v.x;
                As[kq + 1][mrow] = v.y;
                As[kq + 2][mrow] = v.z;
                As[kq + 3][mrow] = v.w;
                idx += 256;
            }
        }
        {
            int idx = tid;
#pragma unroll
            for (int rep = 0; rep < 2; ++rep) {
                const int jrow = idx >> 2;
                const int kq = (idx & 3) * 4;
                const float4 v = *(const float4*)(Wbase + (size_t)jrow * 1024 + k0 + kq);
                Bs[kq + 0][jrow] = v.x;
                Bs[kq + 1][jrow] = v.y;
                Bs[kq + 2][jrow] = v.z;
                Bs[kq + 3][jrow] = v.w;
                idx += 256;
            }
        }
        __syncthreads();
#pragma unroll
        for (int kk = 0; kk < 16; ++kk) {
            float a[8], b[8];
            const float4 a0 = *(const float4*)&As[kk][ty * 8];
            const float4 a1 = *(const float4*)&As[kk][ty * 8 + 4];
            const float4 b0 = *(const float4*)&Bs[kk][tx * 8];
            const float4 b1 = *(const float4*)&Bs[kk][tx * 8 + 4];
            a[0] = a0.x; a[1] = a0.y; a[2] = a0.z; a[3] = a0.w;
            a[4] = a1.x; a[5] = a1.y; a[6] = a1.z; a[7] = a1.w;
            b[0] = b0.x; b[1] = b0.y; b[2] = b0.z; b[3] = b0.w;
            b[4] = b1.x; b[5] = b1.y; b[6] = b1.z; b[7] = b1.w;
#pragma unroll
            for (int i = 0; i < 8; ++i)
#pragma unroll
                for (int j = 0; j < 8; ++j) acc[i][j] += a[i] * b[j];
        }
        __syncthreads();
    }

    const bool isA = (n0 < 512);
#pragma unroll
    for (int i = 0; i < 8; ++i) {
        const int m = m0 + ty * 8 + i;
        const int jbase = n0 + tx * 8;
#pragma unroll
        for (int j = 0; j < 8; ++j) {
            const int jg = jbase + j;
            const float bia = isA ? ba[jg] : bg[jg - 512];
            const float v = acc[i][j] + bia;
            if (isA) Pa[(size_t)m * 512 + jg] = v;
            else     Pgh[(size_t)m * 512 + (jg - 512)] = (f16)v;
        }
    }
}

// ============================================================================
// Phase 2: recurrent scan, tagged self-flagging exchange + LN-fold.
// 64 blocks = 8 row-groups x 8 col-blocks; block = 16 rows x 64 cols, both
// gates; weights (gamma-folded) in registers. Per step: poll tagged h̃ data
// (1 L3 RT), rebuild raw-h̃ LDS tile, MFMA, scalar LN correction, blend,
// publish. Stats polled 1-u64/thread by 256 threads in parallel.
// ============================================================================
__global__ __launch_bounds__(512, 1) void scan5(
    const uint4* __restrict__ WP, const float* __restrict__ gamma,
    const float* __restrict__ beta, const float* __restrict__ Cvec,
    float* po, const f16* __restrict__ Pgh,
    u64* __restrict__ THex,   // [2][8][16][256] tagged (t+1)<<32 | 2xf16
    u64* __restrict__ SHex)   // [2][8][8][16][2] tagged (t+1)<<32 | f32
{
    __shared__ f16 hn[16][512];      // raw h̃, XOR-swizzled
    __shared__ float Dx[16][132];    // MFMA D exchange
    __shared__ float SP[16][16];     // stats partials [row][cb*2+q]

    const int tid = threadIdx.x;
    const int wv = tid >> 6, lane = tid & 63;
    const int bid = blockIdx.x;
    const int rg = bid >> 3, cb = bid & 7;
    const int c0 = cb * 64, r0 = rg * 16;

    // ---- static weight fragments (gamma-folded) into registers ----
    const int tile = (wv < 4) ? (cb * 4 + wv) : (32 + cb * 4 + (wv - 4));
    f16x8 Bf[16];
#pragma unroll
    for (int kf = 0; kf < 16; ++kf) {
        UV4H8 uu; uu.u = WP[(size_t)(tile * 16 + kf) * 64 + lane];
        Bf[kf] = uu.h;
    }

    const int rb = tid >> 5, u = tid & 31;
    const int col0 = c0 + 2 * u;
    // per-thread fold constants + gamma/beta for own 2 output cols
    const float Ca0 = Cvec[col0],        Ca1 = Cvec[col0 + 1];
    const float Ga0 = Cvec[512 + col0],  Ga1 = Cvec[512 + col0 + 1];
    const float Cg0 = Cvec[1024 + col0], Cg1 = Cvec[1024 + col0 + 1];
    const float Gg0 = Cvec[1536 + col0], Gg1 = Cvec[1536 + col0 + 1];
    const float gm0 = gamma[col0], gm1 = gamma[col0 + 1];
    const float bt0 = beta[col0],  bt1 = beta[col0 + 1];

    const int arow = lane & 15;
    const int hi16 = (lane >> 4) * 16;
    const int swzr = (arow & 7) << 4;
    const int swzw = (rb & 7) << 4;
    const char* hrow_r = (const char*)&hn[arow][0];
    char* hrow_w = (char*)&hn[rb][0];
    const int dr = (lane >> 4) * 4;
    const int dc = wv * 16 + (lane & 15);
    const size_t row = (size_t)(r0 + rb);

    // stats-poll role (tid < 256): poll SHex entry (cb=q2>>1, row=srow, q=q2&1)
    const int srow = tid >> 4, q2 = tid & 15;

    float ht0, ht1;
    // ---- t = 0: h_prev = 0 -> a = pa, g = pg ----
    {
        const size_t orow = (row * 512 + 0) * 512 + col0;
        const float2 pa = *(const float2*)(po + orow);
        U32H2 pg; pg.u = *(const unsigned*)(Pgh + orow);
        const float a0 = pa.x, a1 = pa.y;
        const float g0 = (float)pg.h[0], g1 = (float)pg.h[1];
        const float al0 = 1.f / (1.f + __expf(-g0));
        const float al1 = 1.f / (1.f + __expf(-g1));
        const float ac0 = fminf(fmaxf(a0, -15.f), 15.f);
        const float ac1 = fminf(fmaxf(a1, -15.f), 15.f);
        const float e0 = __expf(2.f * ac0), e1 = __expf(2.f * ac1);
        const float th0 = (e0 - 1.f) / (e0 + 1.f);
        const float th1 = (e1 - 1.f) / (e1 + 1.f);
        ht0 = al0 * (th0 - a0) + a0;
        ht1 = al1 * (th1 - a1) + a1;
        float s1 = ht0 + ht1, s2 = ht0 * ht0 + ht1 * ht1;
#pragma unroll
        for (int m = 1; m < 32; m <<= 1) { s1 += __shfl_xor(s1, m); s2 += __shfl_xor(s2, m); }
        U32H2 hw; hw.h[0] = (f16)ht0; hw.h[1] = (f16)ht1;
        st_u64g(THex + (((size_t)0 * 8 + rg) * 16 + rb) * 256 + cb * 32 + u,
                ((u64)1u << 32) | (u64)hw.u);
        if (u == 0) {
            UFI f1; f1.f = s1; UFI f2; f2.f = s2;
            const size_t base = ((((size_t)0 * 8 + rg) * 8 + cb) * 16 + rb) * 2;
            st_u64g(SHex + base,     ((u64)1u << 32) | (u64)f1.u);
            st_u64g(SHex + base + 1, ((u64)1u << 32) | (u64)f2.u);
        }
    }

    for (int t = 1; t < 512; ++t) {
        const int par = (t - 1) & 1;
        const unsigned tg = (unsigned)t;
        const size_t orow = (row * 512 + (size_t)t) * 512 + col0;
        const float2 pa = *(const float2*)(po + orow);
        U32H2 pg; pg.u = *(const unsigned*)(Pgh + orow);

        // ---- poll own h̃ chunk: row rb, cols u*16..+15 (8 tagged u64) ----
        unsigned wlo[8];
        {
            const u64* hp = THex + (((size_t)par * 8 + rg) * 16 + rb) * 256 + u * 8;
            unsigned done = 0;
            while (done != 0xFFu) {
#pragma unroll
                for (int i = 0; i < 8; ++i) {
                    if (!((done >> i) & 1u)) {
                        const u64 x = ld_u64g(hp + i);
                        if ((unsigned)(x >> 32) == tg) { wlo[i] = (unsigned)x; done |= (1u << i); }
                    }
                }
            }
        }
        // ---- poll one stats entry (tid < 256) ----
        if (tid < 256) {
            const u64* sp = SHex + (((size_t)par * 8 + rg) * 8 + (q2 >> 1)) * 32
                          + (size_t)srow * 2 + (q2 & 1);
            u64 x;
            do { x = ld_u64g(sp); } while ((unsigned)(x >> 32) != tg);
            UFI f; f.u = (unsigned)x;
            SP[srow][q2] = f.f;
        }
        // ---- rebuild raw h̃ into hn (swizzled) ----
        {
            UV4H8 o0, o1;
            o0.u = make_uint4(wlo[0], wlo[1], wlo[2], wlo[3]);
            o1.u = make_uint4(wlo[4], wlo[5], wlo[6], wlo[7]);
            *(uint4*)(hrow_w + ((u * 32) ^ swzw)) = o0.u;
            *(uint4*)(hrow_w + ((u * 32 + 16) ^ swzw)) = o1.u;
        }
        __syncthreads();

        // ---- LN stats of h̃_{t-1} (each thread, from SP) ----
        float S1 = 0.f, S2 = 0.f;
#pragma unroll
        for (int q = 0; q < 8; ++q) { S1 += SP[rb][2 * q]; S2 += SP[rb][2 * q + 1]; }
        const float mu = S1 * (1.f / 512.f);
        const float var = S2 * (1.f / 512.f) - mu * mu;
        const float rs = rsqrtf(fmaxf(var, 0.f) + LN_EPS);

        // deferred output write for step t-1 (own cols, fp32 h̃)
        po[orow - 512]     = (ht0 - mu) * rs * gm0 + bt0;
        po[orow - 512 + 1] = (ht1 - mu) * rs * gm1 + bt1;

        // ---- MFMA on raw h̃ (gamma folded into weights) ----
        f32x4 acc = {0.f, 0.f, 0.f, 0.f};
#pragma unroll
        for (int kf = 0; kf < 16; ++kf) {
            const f16x8 Af = *(const f16x8*)(hrow_r + ((kf * 64 + hi16) ^ swzr));
            acc = __builtin_amdgcn_mfma_f32_16x16x32_f16(Af, Bf[kf], acc, 0, 0, 0);
        }
        Dx[dr + 0][dc] = acc[0];
        Dx[dr + 1][dc] = acc[1];
        Dx[dr + 2][dc] = acc[2];
        Dx[dr + 3][dc] = acc[3];
        __syncthreads();

        // ---- scalar LN correction + gated blend ----
        const float murs = mu * rs;
        const float a0 = rs * Dx[rb][2 * u]      - murs * Ga0 + Ca0 + pa.x;
        const float a1 = rs * Dx[rb][2 * u + 1]  - murs * Ga1 + Ca1 + pa.y;
        const float g0 = rs * Dx[rb][64 + 2 * u]     - murs * Gg0 + Cg0 + (float)pg.h[0];
        const float g1 = rs * Dx[rb][64 + 2 * u + 1] - murs * Gg1 + Cg1 + (float)pg.h[1];
        const float al0 = 1.f / (1.f + __expf(-g0));
        const float al1 = 1.f / (1.f + __expf(-g1));
        const float ac0 = fminf(fmaxf(a0, -15.f), 15.f);
        const float ac1 = fminf(fmaxf(a1, -15.f), 15.f);
        const float e0 = __expf(2.f * ac0), e1 = __expf(2.f * ac1);
        const float th0 = (e0 - 1.f) / (e0 + 1.f);
        const float th1 = (e1 - 1.f) / (e1 + 1.f);
        ht0 = al0 * (th0 - a0) + a0;
        ht1 = al1 * (th1 - a1) + a1;

        float s1 = ht0 + ht1, s2 = ht0 * ht0 + ht1 * ht1;
#pragma unroll
        for (int m = 1; m < 32; m <<= 1) { s1 += __shfl_xor(s1, m); s2 += __shfl_xor(s2, m); }

        // ---- publish h̃_t + stats (tag t+1, parity t&1) ----
        {
            U32H2 hw; hw.h[0] = (f16)ht0; hw.h[1] = (f16)ht1;
            st_u64g(THex + (((size_t)(t & 1) * 8 + rg) * 16 + rb) * 256 + cb * 32 + u,
                    ((u64)(unsigned)(t + 1) << 32) | (u64)hw.u);
        }
        if (u == 0) {
            UFI f1; f1.f = s1; UFI f2; f2.f = s2;
            const size_t base = ((((size_t)(t & 1) * 8 + rg) * 8 + cb) * 16 + rb) * 2;
            st_u64g(SHex + base,     ((u64)(unsigned)(t + 1) << 32) | (u64)f1.u);
            st_u64g(SHex + base + 1, ((u64)(unsigned)(t + 1) << 32) | (u64)f2.u);
        }
    }

    // ---- tail: stats of h̃_511 (tag 512, parity 1) -> out[.., 511, ..] ----
    if (tid < 256) {
        const u64* sp = SHex + (((size_t)1 * 8 + rg) * 8 + (q2 >> 1)) * 32
                      + (size_t)srow * 2 + (q2 & 1);
        u64 x;
        do { x = ld_u64g(sp); } while ((unsigned)(x >> 32) != 512u);
        UFI f; f.u = (unsigned)x;
        SP[srow][q2] = f.f;
    }
    __syncthreads();
    {
        float S1 = 0.f, S2 = 0.f;
#pragma unroll
        for (int q = 0; q < 8; ++q) { S1 += SP[rb][2 * q]; S2 += SP[rb][2 * q + 1]; }
        const float mu = S1 * (1.f / 512.f);
        const float var = S2 * (1.f / 512.f) - mu * mu;
        const float rs = rsqrtf(fmaxf(var, 0.f) + LN_EPS);
        const size_t orow = (row * 512 + 511) * 512 + col0;
        po[orow]     = (ht0 - mu) * rs * gm0 + bt0;
        po[orow + 1] = (ht1 - mu) * rs * gm1 + bt1;
    }
}

extern "C" void kernel_launch(void* const* d_in, const int* in_sizes, int n_in,
                              void* d_out, int out_size, void* d_ws, size_t ws_size,
                              hipStream_t stream) {
    (void)in_sizes; (void)n_in; (void)out_size; (void)ws_size;
    const float* X     = (const float*)d_in[0];
    const float* Wa    = (const float*)d_in[1];
    const float* Wg    = (const float*)d_in[2];
    const float* ba    = (const float*)d_in[3];
    const float* bg    = (const float*)d_in[4];
    const float* gamma = (const float*)d_in[5];
    const float* beta  = (const float*)d_in[6];
    float* out = (float*)d_out;

    char* ws = (char*)d_ws;
    f16*    Pgh  = (f16*)ws;                      // 67108864 B
    uint4*  WP   = (uint4*)(ws + 67108864);       // 1048576 B
    u64*    THex = (u64*)(ws + 68157440);         // 524288 B (65536 u64)
    u64*    SHex = (u64*)(ws + 68681728);         // 32768 B  (4096 u64)
    float*  Cvec = (float*)(ws + 68714496);       // 8192 B

    init_ex<<<dim3(272), dim3(256), 0, stream>>>(THex, 69632);
    pack_wfrags<<<dim3(256), dim3(256), 0, stream>>>(Wa, Wg, gamma, WP);
    precompute_consts<<<dim3(512), dim3(64), 0, stream>>>(Wa, Wg, gamma, beta, Cvec);
    precompute_gemm<<<dim3(4096), dim3(256), 0, stream>>>(X, Wa, Wg, ba, bg, out, Pgh);

    void* args[] = { (void*)&WP, (void*)&gamma, (void*)&beta, (void*)&Cvec,
                     (void*)&out, (void*)&Pgh, (void*)&THex, (void*)&SHex };
    hipLaunchCooperativeKernel((const void*)scan5, dim3(64), dim3(512),
                               args, 0, stream);
}

// Round 6
// 2192.821 us; speedup vs baseline: 10.1263x; 1.2559x over previous
//
#include <hip/hip_runtime.h>
#include <math.h>

typedef _Float16 f16;
typedef _Float16 f16x8 __attribute__((ext_vector_type(8)));
typedef float f32x4 __attribute__((ext_vector_type(4)));
typedef unsigned long long u64;

union U32H2 { unsigned u; f16 h[2]; };
union UV4H8 { uint4 u; f16x8 h; f16 e[8]; };

#define LN_EPS 1e-5f

// ---- cache-bypassing (L3-coherent) 8-byte atomics, relaxed agent scope ----
__device__ __forceinline__ void st_u64g(u64* p, u64 v) {
    __hip_atomic_store(p, v, __ATOMIC_RELAXED, __HIP_MEMORY_SCOPE_AGENT);
}
__device__ __forceinline__ u64 ld_u64g(const u64* p) {
    return __hip_atomic_load(p, __ATOMIC_RELAXED, __HIP_MEMORY_SCOPE_AGENT);
}

// ============================================================================
// init: zero tagged-exchange buffer (every launch — replay safety)
// ============================================================================
__global__ __launch_bounds__(256) void init_ex(u64* p, int n) {
    const int i = blockIdx.x * 256 + threadIdx.x;
    if (i < n) p[i] = 0ull;
}

// ============================================================================
// Phase 0a: pack h-part weights, GAMMA-FOLDED, into MFMA B-fragment order.
//   W'[col][k] = W[col][k] * gamma[k]
//   col = (tile%32)*16 + (lane&15),  k = kf*32 + (lane>>4)*8 + j
// tiles 0..31 = a-gate, 32..63 = g-gate.
// ============================================================================
__global__ __launch_bounds__(256) void pack_wfrags(
    const float* __restrict__ Wa, const float* __restrict__ Wg,
    const float* __restrict__ gamma, uint4* __restrict__ WP)
{
    const int t = blockIdx.x * 256 + threadIdx.x;   // 0..65535
    const int lane = t & 63;
    const int kf = (t >> 6) & 15;
    const int tile = t >> 10;
    const float* W = (tile < 32) ? Wa : Wg;
    const int col = (tile & 31) * 16 + (lane & 15);
    const int k0 = kf * 32 + (lane >> 4) * 8;
    const float* src = W + (size_t)col * 1024 + k0;
    UV4H8 u;
#pragma unroll
    for (int j = 0; j < 8; ++j) u.e[j] = (f16)(src[j] * gamma[k0 + j]);
    WP[t] = u.u;
}

// ============================================================================
// Phase 0b: fold constants:
//   Cvec[0][o]=Wa[o]·beta  Cvec[1][o]=Wa[o]·gamma  Cvec[2][o]=Wg[o]·beta
//   Cvec[3][o]=Wg[o]·gamma   (h-part k<512, fp32)
// ============================================================================
__global__ __launch_bounds__(64) void precompute_consts(
    const float* __restrict__ Wa, const float* __restrict__ Wg,
    const float* __restrict__ gamma, const float* __restrict__ beta,
    float* __restrict__ Cvec)
{
    const int o = blockIdx.x;
    const int l = threadIdx.x;
    const float* wa = Wa + (size_t)o * 1024;
    const float* wg = Wg + (size_t)o * 1024;
    float ca = 0.f, ga = 0.f, cg = 0.f, gg = 0.f;
    for (int k = l; k < 512; k += 64) {
        const float bk = beta[k], gk = gamma[k], a = wa[k], g = wg[k];
        ca += a * bk; ga += a * gk; cg += g * bk; gg += g * gk;
    }
#pragma unroll
    for (int m = 1; m < 64; m <<= 1) {
        ca += __shfl_xor(ca, m); ga += __shfl_xor(ga, m);
        cg += __shfl_xor(cg, m); gg += __shfl_xor(gg, m);
    }
    if (l == 0) {
        Cvec[o] = ca; Cvec[512 + o] = ga; Cvec[1024 + o] = cg; Cvec[1536 + o] = gg;
    }
}

// ============================================================================
// Phase 1: precompute P = X @ Wx^T + bias (x-part = cols 512..1023 of W).
// Pa -> d_out (fp32); Pg -> ws as f16. (unchanged — verified)
// ============================================================================
__global__ __launch_bounds__(256) void precompute_gemm(
    const float* __restrict__ X, const float* __restrict__ Wa,
    const float* __restrict__ Wg, const float* __restrict__ ba,
    const float* __restrict__ bg, float* __restrict__ Pa,
    f16* __restrict__ Pgh)
{
    __shared__ float As[16][132];
    __shared__ float Bs[16][132];
    const int bid = blockIdx.x;
    const int bn = bid & 7;
    const int bm = bid >> 3;
    const int tid = threadIdx.x;
    const int tx = tid & 15;
    const int ty = tid >> 4;

    const int m0 = bm * 128;
    const int n0 = bn * 128;

    const float* Wbase = (n0 < 512) ? (Wa + (size_t)n0 * 1024 + 512)
                                    : (Wg + (size_t)(n0 - 512) * 1024 + 512);

    float acc[8][8];
#pragma unroll
    for (int i = 0; i < 8; ++i)
#pragma unroll
        for (int j = 0; j < 8; ++j) acc[i][j] = 0.f;

    for (int k0 = 0; k0 < 512; k0 += 16) {
        {
            int idx = tid;
#pragma unroll
            for (int rep = 0; rep < 2; ++rep) {
                const int mrow = idx >> 2;
                const int kq = (idx & 3) * 4;
                const float4 v = *(const float4*)(X + (size_t)(m0 + mrow) * 512 + k0 + kq);
                As[kq + 0][mrow] = v.x;
                As[kq + 1][mrow] = v.y;
                As[kq + 2][mrow] = v.z;
                As[kq + 3][mrow] = v.w;
                idx += 256;
            }
        }
        {
            int idx = tid;
#pragma unroll
            for (int rep = 0; rep < 2; ++rep) {
                const int jrow = idx >> 2;
                const int kq = (idx & 3) * 4;
                const float4 v = *(const float4*)(Wbase + (size_t)jrow * 1024 + k0 + kq);
                Bs[kq + 0][jrow] = v.x;
                Bs[kq + 1][jrow] = v.y;
                Bs[kq + 2][jrow] = v.z;
                Bs[kq + 3][jrow] = v.w;
                idx += 256;
            }
        }
        __syncthreads();
#pragma unroll
        for (int kk = 0; kk < 16; ++kk) {
            float a[8], b[8];
            const float4 a0 = *(const float4*)&As[kk][ty * 8];
            const float4 a1 = *(const float4*)&As[kk][ty * 8 + 4];
            const float4 b0 = *(const float4*)&Bs[kk][tx * 8];
            const float4 b1 = *(const float4*)&Bs[kk][tx * 8 + 4];
            a[0] = a0.x; a[1] = a0.y; a[2] = a0.z; a[3] = a0.w;
            a[4] = a1.x; a[5] = a1.y; a[6] = a1.z; a[7] = a1.w;
            b[0] = b0.x; b[1] = b0.y; b[2] = b0.z; b[3] = b0.w;
            b[4] = b1.x; b[5] = b1.y; b[6] = b1.z; b[7] = b1.w;
#pragma unroll
            for (int i = 0; i < 8; ++i)
#pragma unroll
                for (int j = 0; j < 8; ++j) acc[i][j] += a[i] * b[j];
        }
        __syncthreads();
    }

    const bool isA = (n0 < 512);
#pragma unroll
    for (int i = 0; i < 8; ++i) {
        const int m = m0 + ty * 8 + i;
        const int jbase = n0 + tx * 8;
#pragma unroll
        for (int j = 0; j < 8; ++j) {
            const int jg = jbase + j;
            const float bia = isA ? ba[jg] : bg[jg - 512];
            const float v = acc[i][j] + bia;
            if (isA) Pa[(size_t)m * 512 + jg] = v;
            else     Pgh[(size_t)m * 512 + (jg - 512)] = (f16)v;
        }
    }
}

// ============================================================================
// Phase 2: recurrent scan, v6.
//  - coalesced tagged poll: thread (rb,u) polls u64 idx {i*32+u}, i=0..7
//    (each poll instruction = contiguous 512B wave read)
//  - LN stats computed LOCALLY from polled f16 h̃ (no stats exchange at all)
//  - conflict-free LDS rebuild (8x ds_write_b32, contiguous per instruction)
//  - 2-accumulator MFMA
// ============================================================================
__global__ __launch_bounds__(512, 1) void scan6(
    const uint4* __restrict__ WP, const float* __restrict__ gamma,
    const float* __restrict__ beta, const float* __restrict__ Cvec,
    float* po, const f16* __restrict__ Pgh,
    u64* __restrict__ THex)   // [2][8][16][256] tagged (t+1)<<32 | 2xf16
{
    __shared__ f16 hn[16][512];      // raw h̃, XOR-swizzled
    __shared__ float Dx[16][132];    // MFMA D exchange

    const int tid = threadIdx.x;
    const int wv = tid >> 6, lane = tid & 63;
    const int bid = blockIdx.x;
    const int rg = bid >> 3, cb = bid & 7;
    const int c0 = cb * 64, r0 = rg * 16;

    // ---- static weight fragments (gamma-folded) into registers ----
    const int tile = (wv < 4) ? (cb * 4 + wv) : (32 + cb * 4 + (wv - 4));
    f16x8 Bf[16];
#pragma unroll
    for (int kf = 0; kf < 16; ++kf) {
        UV4H8 uu; uu.u = WP[(size_t)(tile * 16 + kf) * 64 + lane];
        Bf[kf] = uu.h;
    }

    const int rb = tid >> 5, u = tid & 31;
    const int col0 = c0 + 2 * u;
    const float Ca0 = Cvec[col0],        Ca1 = Cvec[col0 + 1];
    const float Ga0 = Cvec[512 + col0],  Ga1 = Cvec[512 + col0 + 1];
    const float Cg0 = Cvec[1024 + col0], Cg1 = Cvec[1024 + col0 + 1];
    const float Gg0 = Cvec[1536 + col0], Gg1 = Cvec[1536 + col0 + 1];
    const float gm0 = gamma[col0], gm1 = gamma[col0 + 1];
    const float bt0 = beta[col0],  bt1 = beta[col0 + 1];

    const int arow = lane & 15;
    const int hi16 = (lane >> 4) * 16;
    const int swzr = (arow & 7) << 4;
    const int swzw = (rb & 7) << 4;
    const char* hrow_r = (const char*)&hn[arow][0];
    char* hrow_w = (char*)&hn[rb][0];
    const int dr = (lane >> 4) * 4;
    const int dc = wv * 16 + (lane & 15);
    const size_t row = (size_t)(r0 + rb);
    // publish slot (producer layout): row*256 + cb*32 + u
    u64* pub0 = THex + ((size_t)0 * 8 + rg) * 4096 + (size_t)rb * 256 + cb * 32 + u;
    u64* pub1 = THex + ((size_t)1 * 8 + rg) * 4096 + (size_t)rb * 256 + cb * 32 + u;
    // poll base (consumer layout): row rb, entries i*32+u
    const u64* pol0 = THex + ((size_t)0 * 8 + rg) * 4096 + (size_t)rb * 256 + u;
    const u64* pol1 = THex + ((size_t)1 * 8 + rg) * 4096 + (size_t)rb * 256 + u;

    float ht0, ht1;
    // ---- t = 0: h_prev = 0 -> a = pa, g = pg ----
    {
        const size_t orow = (row * 512 + 0) * 512 + col0;
        const float2 pa = *(const float2*)(po + orow);
        U32H2 pg; pg.u = *(const unsigned*)(Pgh + orow);
        const float a0 = pa.x, a1 = pa.y;
        const float g0 = (float)pg.h[0], g1 = (float)pg.h[1];
        const float al0 = 1.f / (1.f + __expf(-g0));
        const float al1 = 1.f / (1.f + __expf(-g1));
        const float ac0 = fminf(fmaxf(a0, -15.f), 15.f);
        const float ac1 = fminf(fmaxf(a1, -15.f), 15.f);
        const float e0 = __expf(2.f * ac0), e1 = __expf(2.f * ac1);
        const float th0 = (e0 - 1.f) / (e0 + 1.f);
        const float th1 = (e1 - 1.f) / (e1 + 1.f);
        ht0 = al0 * (th0 - a0) + a0;
        ht1 = al1 * (th1 - a1) + a1;
        U32H2 hw; hw.h[0] = (f16)ht0; hw.h[1] = (f16)ht1;
        st_u64g(pub0, ((u64)1u << 32) | (u64)hw.u);
    }

    for (int t = 1; t < 512; ++t) {
        const unsigned tg = (unsigned)t;
        const u64* hp = ((t - 1) & 1) ? pol1 : pol0;
        const size_t orow = (row * 512 + (size_t)t) * 512 + col0;
        const float2 pa = *(const float2*)(po + orow);
        U32H2 pg; pg.u = *(const unsigned*)(Pgh + orow);

        // ---- coalesced poll: 8 u64 at stride 32 (contiguous across lanes) ----
        u64 v[8];
        for (;;) {
#pragma unroll
            for (int i = 0; i < 8; ++i) v[i] = ld_u64g(hp + i * 32);
            bool ok = true;
#pragma unroll
            for (int i = 0; i < 8; ++i) ok &= ((unsigned)(v[i] >> 32) == tg);
            if (ok) break;
        }

        // ---- local LN stats of h̃_{t-1} (f16-derived, full row via shfl) ----
        float s1 = 0.f, s2 = 0.f;
#pragma unroll
        for (int i = 0; i < 8; ++i) {
            U32H2 hh; hh.u = (unsigned)v[i];
            const float x0 = (float)hh.h[0], x1 = (float)hh.h[1];
            s1 += x0 + x1; s2 += x0 * x0 + x1 * x1;
        }
#pragma unroll
        for (int m = 1; m < 32; m <<= 1) { s1 += __shfl_xor(s1, m); s2 += __shfl_xor(s2, m); }
        const float mu = s1 * (1.f / 512.f);
        const float var = s2 * (1.f / 512.f) - mu * mu;
        const float rs = rsqrtf(fmaxf(var, 0.f) + LN_EPS);
        const float murs = mu * rs;

        // ---- rebuild raw h̃ into hn (swizzled, conflict-free b32 writes) ----
#pragma unroll
        for (int i = 0; i < 8; ++i) {
            *(unsigned*)(hrow_w + ((128 * i + 4 * u) ^ swzw)) = (unsigned)v[i];
        }
        __syncthreads();

        // ---- MFMA on raw h̃ (gamma folded into weights), 2 accumulators ----
        f32x4 acc0 = {0.f, 0.f, 0.f, 0.f};
        f32x4 acc1 = {0.f, 0.f, 0.f, 0.f};
#pragma unroll
        for (int kf = 0; kf < 8; ++kf) {
            const f16x8 Af0 = *(const f16x8*)(hrow_r + ((kf * 64 + hi16) ^ swzr));
            acc0 = __builtin_amdgcn_mfma_f32_16x16x32_f16(Af0, Bf[kf], acc0, 0, 0, 0);
            const f16x8 Af1 = *(const f16x8*)(hrow_r + (((kf + 8) * 64 + hi16) ^ swzr));
            acc1 = __builtin_amdgcn_mfma_f32_16x16x32_f16(Af1, Bf[kf + 8], acc1, 0, 0, 0);
        }
        Dx[dr + 0][dc] = acc0[0] + acc1[0];
        Dx[dr + 1][dc] = acc0[1] + acc1[1];
        Dx[dr + 2][dc] = acc0[2] + acc1[2];
        Dx[dr + 3][dc] = acc0[3] + acc1[3];
        __syncthreads();

        // ---- scalar LN correction + gated blend ----
        const float a0 = rs * Dx[rb][2 * u]          - murs * Ga0 + Ca0 + pa.x;
        const float a1 = rs * Dx[rb][2 * u + 1]      - murs * Ga1 + Ca1 + pa.y;
        const float g0 = rs * Dx[rb][64 + 2 * u]     - murs * Gg0 + Cg0 + (float)pg.h[0];
        const float g1 = rs * Dx[rb][64 + 2 * u + 1] - murs * Gg1 + Cg1 + (float)pg.h[1];
        const float al0 = 1.f / (1.f + __expf(-g0));
        const float al1 = 1.f / (1.f + __expf(-g1));
        const float ac0 = fminf(fmaxf(a0, -15.f), 15.f);
        const float ac1 = fminf(fmaxf(a1, -15.f), 15.f);
        const float e0 = __expf(2.f * ac0), e1 = __expf(2.f * ac1);
        const float th0 = (e0 - 1.f) / (e0 + 1.f);
        const float th1 = (e1 - 1.f) / (e1 + 1.f);
        const float nt0 = al0 * (th0 - a0) + a0;
        const float nt1 = al1 * (th1 - a1) + a1;

        // ---- publish h̃_t FIRST (critical path for consumers) ----
        {
            U32H2 hw; hw.h[0] = (f16)nt0; hw.h[1] = (f16)nt1;
            st_u64g((t & 1) ? pub1 : pub0, ((u64)(unsigned)(t + 1) << 32) | (u64)hw.u);
        }
        // deferred output write for step t-1 (fp32 h̃, f16-derived stats)
        po[orow - 512]     = (ht0 - mu) * rs * gm0 + bt0;
        po[orow - 512 + 1] = (ht1 - mu) * rs * gm1 + bt1;
        ht0 = nt0; ht1 = nt1;
        __syncthreads();
    }

    // ---- tail: stats of h̃_511 (tag 512, parity 1) -> out[.., 511, ..] ----
    {
        u64 v[8];
        for (;;) {
#pragma unroll
            for (int i = 0; i < 8; ++i) v[i] = ld_u64g(pol1 + i * 32);
            bool ok = true;
#pragma unroll
            for (int i = 0; i < 8; ++i) ok &= ((unsigned)(v[i] >> 32) == 512u);
            if (ok) break;
        }
        float s1 = 0.f, s2 = 0.f;
#pragma unroll
        for (int i = 0; i < 8; ++i) {
            U32H2 hh; hh.u = (unsigned)v[i];
            const float x0 = (float)hh.h[0], x1 = (float)hh.h[1];
            s1 += x0 + x1; s2 += x0 * x0 + x1 * x1;
        }
#pragma unroll
        for (int m = 1; m < 32; m <<= 1) { s1 += __shfl_xor(s1, m); s2 += __shfl_xor(s2, m); }
        const float mu = s1 * (1.f / 512.f);
        const float var = s2 * (1.f / 512.f) - mu * mu;
        const float rs = rsqrtf(fmaxf(var, 0.f) + LN_EPS);
        const size_t orow = (row * 512 + 511) * 512 + col0;
        po[orow]     = (ht0 - mu) * rs * gm0 + bt0;
        po[orow + 1] = (ht1 - mu) * rs * gm1 + bt1;
    }
}

extern "C" void kernel_launch(void* const* d_in, const int* in_sizes, int n_in,
                              void* d_out, int out_size, void* d_ws, size_t ws_size,
                              hipStream_t stream) {
    (void)in_sizes; (void)n_in; (void)out_size; (void)ws_size;
    const float* X     = (const float*)d_in[0];
    const float* Wa    = (const float*)d_in[1];
    const float* Wg    = (const float*)d_in[2];
    const float* ba    = (const float*)d_in[3];
    const float* bg    = (const float*)d_in[4];
    const float* gamma = (const float*)d_in[5];
    const float* beta  = (const float*)d_in[6];
    float* out = (float*)d_out;

    char* ws = (char*)d_ws;
    f16*    Pgh  = (f16*)ws;                      // 67108864 B
    uint4*  WP   = (uint4*)(ws + 67108864);       // 1048576 B
    u64*    THex = (u64*)(ws + 68157440);         // 524288 B (65536 u64)
    float*  Cvec = (float*)(ws + 68681728);       // 8192 B

    init_ex<<<dim3(256), dim3(256), 0, stream>>>(THex, 65536);
    pack_wfrags<<<dim3(256), dim3(256), 0, stream>>>(Wa, Wg, gamma, WP);
    precompute_consts<<<dim3(512), dim3(64), 0, stream>>>(Wa, Wg, gamma, beta, Cvec);
    precompute_gemm<<<dim3(4096), dim3(256), 0, stream>>>(X, Wa, Wg, ba, bg, out, Pgh);

    void* args[] = { (void*)&WP, (void*)&gamma, (void*)&beta, (void*)&Cvec,
                     (void*)&out, (void*)&Pgh, (void*)&THex };
    hipLaunchCooperativeKernel((const void*)scan6, dim3(64), dim3(512),
                               args, 0, stream);
}